// Round 1
// baseline (14393.779 us; speedup 1.0000x reference)
//
#include <hip/hip_runtime.h>

// CeNN layer, f32 direct conv version.
// N=16, C=64, H=W=128. 12 conv passes (IC, state0, 10 iterations).
// Iteration fused: dst = 0.1*(conv3x3(nonlin(src),A) + 9*src_center + A_b + IC)
// Last iteration additionally applies nonlin and writes d_out.

#define HH 128
#define WW 128
#define CCH 64
#define NBATCH 16

__device__ __forceinline__ float nonlin(float x) {
    // y = min(x, 1 + a*(x-1)) = min(x, a*x + (1-a))
    // r = max(y, -1 + a*(y+1)) = max(y, a*y - (1-a))
    const float A = 0.01f;
    float y = fminf(x, fmaf(A, x, 1.0f - A));
    return fmaxf(y, fmaf(A, y, -(1.0f - A)));
}

// MODE 0: dst = conv(src,w)+bias                      (state init, extra unused)
// MODE 1: dst = conv(src,w)+bias+extra[co]            (input coupling, extra=Z)
// MODE 2: dst = 0.1*(conv(nonlin(src),w)+9*center+bias+extra[idx])  (iter, extra=IC)
// MODE 3: MODE 2 followed by nonlin, writes final output
template<int MODE>
__global__ __launch_bounds__(256, 2)
void conv_pass(const float* __restrict__ src,
               const float* __restrict__ wgt,
               const float* __restrict__ bias,
               const float* __restrict__ extra,
               float* __restrict__ dst)
{
    __shared__ float tile[32][18][18];   // 41472 B
    const int tx = threadIdx.x, ty = threadIdx.y;
    const int t  = ty * 16 + tx;
    const int bx = blockIdx.x, by = blockIdx.y, n = blockIdx.z;
    const int gx = bx * 16 + tx, gy = by * 16 + ty;

    float acc[64];
    #pragma unroll
    for (int i = 0; i < 64; ++i) acc[i] = 0.0f;

    #pragma unroll
    for (int chunk = 0; chunk < 2; ++chunk) {
        // ---- stage 32 input channels (with halo, zero-padded) ----
        const float* sbase = src + ((size_t)n * CCH + chunk * 32) * (size_t)(HH * WW);
        for (int idx = t; idx < 32 * 18 * 18; idx += 256) {
            int ci  = idx / 324;
            int rem = idx - ci * 324;
            int yy  = rem / 18;
            int xx  = rem - yy * 18;
            int sy  = by * 16 + yy - 1;
            int sx  = bx * 16 + xx - 1;
            float v = 0.0f;
            if ((unsigned)sy < (unsigned)HH && (unsigned)sx < (unsigned)WW)
                v = sbase[((size_t)ci * HH + sy) * WW + sx];
            tile[ci][yy][xx] = v;
        }
        __syncthreads();

        // ---- center term for the Euler update (raw state, coeff 9 = 0.9/0.1) ----
        if constexpr (MODE >= 2) {
            #pragma unroll
            for (int cl = 0; cl < 32; ++cl)
                acc[chunk * 32 + cl] += 9.0f * tile[cl][ty + 1][tx + 1];
        }

        // ---- conv accumulate ----
        #pragma unroll 1
        for (int cl = 0; cl < 32; ++cl) {
            float v[9];
            #pragma unroll
            for (int dy = 0; dy < 3; ++dy)
                #pragma unroll
                for (int dx = 0; dx < 3; ++dx)
                    v[dy * 3 + dx] = tile[cl][ty + dy][tx + dx];
            if constexpr (MODE >= 2) {
                #pragma unroll
                for (int k = 0; k < 9; ++k) v[k] = nonlin(v[k]);
            }
            const int ci = chunk * 32 + cl;
            #pragma unroll
            for (int co = 0; co < 64; ++co) {
                const float* wc = wgt + ((size_t)co * CCH + ci) * 9;  // uniform -> s_load
                #pragma unroll
                for (int k = 0; k < 9; ++k)
                    acc[co] = fmaf(wc[k], v[k], acc[co]);
            }
        }
        __syncthreads();
    }

    // ---- epilogue ----
    const size_t pix = (size_t)gy * WW + gx;
    #pragma unroll
    for (int co = 0; co < 64; ++co) {
        float r = acc[co] + bias[co];
        const size_t oidx = ((size_t)n * CCH + co) * (size_t)(HH * WW) + pix;
        if constexpr (MODE == 1) r += extra[co];
        if constexpr (MODE >= 2) {
            r = 0.1f * (r + extra[oidx]);
            if constexpr (MODE == 3) r = nonlin(r);
        }
        dst[oidx] = r;
    }
}

extern "C" void kernel_launch(void* const* d_in, const int* in_sizes, int n_in,
                              void* d_out, int out_size, void* d_ws, size_t ws_size,
                              hipStream_t stream) {
    const float* x  = (const float*)d_in[0];
    const float* rw = (const float*)d_in[1];
    const float* rb = (const float*)d_in[2];
    const float* aw = (const float*)d_in[3];
    const float* ab = (const float*)d_in[4];
    const float* bw = (const float*)d_in[5];
    const float* bb = (const float*)d_in[6];
    const float* z  = (const float*)d_in[7];
    float* out = (float*)d_out;

    const size_t plane = (size_t)NBATCH * CCH * HH * WW;  // 16.78M floats
    float* ic = (float*)d_ws;          // input coupling, persists all iters
    float* s1 = ic + plane;            // state ping buffer (pong = d_out)

    dim3 blk(16, 16, 1), grd(WW / 16, HH / 16, NBATCH);

    // input_coupling = conv(x, B_w) + B_b + Z
    conv_pass<1><<<grd, blk, 0, stream>>>(x, bw, bb, z, ic);
    // state0 = conv(x, rescale_w) + rescale_b   -> lives in d_out (even slot)
    conv_pass<0><<<grd, blk, 0, stream>>>(x, rw, rb, nullptr, out);

    for (int i = 0; i < 10; ++i) {
        const float* s = (i & 1) ? s1 : out;
        float*       d = (i & 1) ? out : s1;
        if (i == 9)
            conv_pass<3><<<grd, blk, 0, stream>>>(s, aw, ab, ic, out);  // i=9 odd: s1 -> d_out
        else
            conv_pass<2><<<grd, blk, 0, stream>>>(s, aw, ab, ic, d);
    }
}

// Round 2
// 1289.147 us; speedup vs baseline: 11.1653x; 11.1653x over previous
//
#include <hip/hip_runtime.h>

// CeNN layer via bf16 MFMA implicit GEMM.
// 12 passes: state0, ICp, 10 fused iterations.
// Iter: dst = 0.9*src + 0.1*conv3x3(nonlin(src), A_w) + ICp,  ICp = 0.1*(A_b + conv3x3(x,B_w) + B_b + Z)
// Per block: 64 cout x 64 px wide x 8 rows. K = tap*64+cin (576), MFMA 16x16x32 bf16.

typedef short  bf16x8 __attribute__((ext_vector_type(8)));
typedef float  f32x4  __attribute__((ext_vector_type(4)));

#define HH 128
#define WW 128
#define NCH 64
#define GROWS 8
#define NSLOT (GROWS + 2)      // staged rows: y0-1 .. y0+8
#define XS 64                  // output strip width
#define NC 66                  // staged cols (x0-1 .. x0+64)
#define ROWB 128               // 64 cin * 2B per col
#define SLOTB (NC * ROWB)      // 8448 B per row
#define ACTB (NSLOT * SLOTB)   // 84480 B
#define WCHUNKS 4608           // 18 kb * 4 cb * 64 lanes
#define WLDSB (WCHUNKS * 16)   // 73728 B
#define LDS_BYTES (ACTB + WLDSB)  // 158208 <= 163840

__device__ __forceinline__ float nonlin(float x) {
    const float A = 0.01f;
    float y = fminf(x, fmaf(A, x, 1.0f - A));
    return fmaxf(y, fmaf(A, y, -(1.0f - A)));
}
__device__ __forceinline__ unsigned short f2bf(float f) {
    unsigned int u = __float_as_uint(f);
    u += 0x7fffu + ((u >> 16) & 1u);       // round-to-nearest-even
    return (unsigned short)(u >> 16);
}

// MODE 0: dst = conv(src,w)+b1                      (state0; no nonlin at stage)
// MODE 1: dst = 0.1*(conv(src,w)+b1+b2+b3)          (ICp; b1=B_b, b2=Z, b3=A_b)
// MODE 2: dst = 0.1*conv(nonlin(src),w)+0.9*src+icp (iteration)
// MODE 3: MODE 2 + final nonlin
template<int MODE>
__global__ __launch_bounds__(256, 1)
void cenn_conv(const float* __restrict__ src,
               const float* __restrict__ wgt,
               const float* __restrict__ b1,
               const float* __restrict__ b2,
               const float* __restrict__ b3,
               const float* __restrict__ icp,
               float* __restrict__ dst)
{
    extern __shared__ __align__(16) char smem[];
    char* actl = smem;          // swizzled bf16 activations
    char* wl   = smem + ACTB;   // fragment-ordered bf16 weights

    const int tid  = threadIdx.x;
    const int lane = tid & 63;
    const int wv   = tid >> 6;
    const int l15  = lane & 15;
    const int g4   = lane >> 4;
    const int x0   = blockIdx.x * XS;
    const int y0   = blockIdx.y * GROWS;
    const int n    = blockIdx.z;

    // ---- stage + transform weights into MFMA fragment order ----
    // chunk = (kb*4+cb)*64 + lane ; value j : k = kb*32 + (lane>>4)*8 + j
    // k -> tap = k>>6 (3x3 pos, row-major), cin = k&63 ; w layout [cout][cin][tap]
    for (int i = 0; i < 18; ++i) {
        int chunk = i * 256 + tid;
        int kb = chunk >> 8;
        int cb = (chunk >> 6) & 3;
        int ln = chunk & 63;
        int cout = cb * 16 + (ln & 15);
        int g = ln >> 4;
        unsigned short h[8];
        #pragma unroll
        for (int j = 0; j < 8; ++j) {
            int k   = kb * 32 + g * 8 + j;
            int tap = k >> 6;
            int cin = k & 63;
            h[j] = f2bf(wgt[(cout * 64 + cin) * 9 + tap]);
        }
        uint4 v;
        v.x = (unsigned)h[0] | ((unsigned)h[1] << 16);
        v.y = (unsigned)h[2] | ((unsigned)h[3] << 16);
        v.z = (unsigned)h[4] | ((unsigned)h[5] << 16);
        v.w = (unsigned)h[6] | ((unsigned)h[7] << 16);
        *(uint4*)(wl + chunk * 16) = v;
    }

    // ---- stage activations: NSLOT rows of [66 cols][64 cin] bf16, XOR-swizzled ----
    for (int r = 0; r < NSLOT; ++r) {
        int y = y0 + r - 1;
        bool yok = (unsigned)y < (unsigned)HH;
        for (int idx = tid; idx < NC * 8; idx += 256) {
            int c   = idx % NC;        // staged col, image x = x0 + c - 1
            int cb8 = idx / NC;        // cin block of 8
            int x   = x0 + c - 1;
            uint4 v = {0u, 0u, 0u, 0u};
            if (yok && (unsigned)x < (unsigned)WW) {
                const float* p = src + ((size_t)(n * NCH + cb8 * 8) * HH + y) * WW + x;
                unsigned short h[8];
                #pragma unroll
                for (int j = 0; j < 8; ++j) {
                    float f = p[(size_t)j * HH * WW];
                    if (MODE >= 2) f = nonlin(f);
                    h[j] = f2bf(f);
                }
                v.x = (unsigned)h[0] | ((unsigned)h[1] << 16);
                v.y = (unsigned)h[2] | ((unsigned)h[3] << 16);
                v.z = (unsigned)h[4] | ((unsigned)h[5] << 16);
                v.w = (unsigned)h[6] | ((unsigned)h[7] << 16);
            }
            int off = r * SLOTB + c * ROWB + ((cb8 * 16) ^ ((c & 7) << 4));
            *(uint4*)(actl + off) = v;
        }
    }
    __syncthreads();

    // ---- MFMA main loop: 18 K-blocks of 32 ----
    // wave wv owns units u = wv*8+i : row = u>>2 (0..7), pf = u&3 (16-px frag)
    f32x4 acc[4][8];
    #pragma unroll
    for (int a = 0; a < 4; ++a)
        #pragma unroll
        for (int b = 0; b < 8; ++b)
            acc[a][b] = (f32x4){0.f, 0.f, 0.f, 0.f};

    for (int kb = 0; kb < 18; ++kb) {
        int tap = kb >> 1;
        int dy  = tap / 3;
        int dx  = tap - dy * 3;
        int cinByte = ((kb & 1) * 32 + g4 * 8) * 2;

        bf16x8 af[4];
        #pragma unroll
        for (int cb = 0; cb < 4; ++cb)
            af[cb] = *(const bf16x8*)(wl + ((kb * 4 + cb) * 64 + lane) * 16);

        bf16x8 bfr[8];
        #pragma unroll
        for (int i = 0; i < 8; ++i) {
            int u   = wv * 8 + i;
            int row = u >> 2;
            int pf  = u & 3;
            int c   = pf * 16 + l15 + dx;
            bfr[i] = *(const bf16x8*)(actl + (row + dy) * SLOTB + c * ROWB
                                      + (cinByte ^ ((c & 7) << 4)));
        }

        #pragma unroll
        for (int cb = 0; cb < 4; ++cb)
            #pragma unroll
            for (int i = 0; i < 8; ++i)
                acc[cb][i] = __builtin_amdgcn_mfma_f32_16x16x32_bf16(
                    af[cb], bfr[i], acc[cb][i], 0, 0, 0);
    }

    // ---- epilogue: D lane map: pixel = lane&15, cout = cb*16 + (lane>>4)*4 + r ----
    #pragma unroll
    for (int cb = 0; cb < 4; ++cb) {
        #pragma unroll
        for (int i = 0; i < 8; ++i) {
            int u   = wv * 8 + i;
            int row = u >> 2;
            int pf  = u & 3;
            int x   = x0 + pf * 16 + l15;
            int y   = y0 + row;
            #pragma unroll
            for (int r = 0; r < 4; ++r) {
                int cout = cb * 16 + g4 * 4 + r;
                size_t idx = ((size_t)(n * NCH + cout) * HH + y) * WW + x;
                float v = acc[cb][i][r];
                if constexpr (MODE == 0) {
                    v += b1[cout];
                } else if constexpr (MODE == 1) {
                    v = 0.1f * (v + b1[cout] + b2[cout] + b3[cout]);
                } else {
                    v = 0.1f * v + 0.9f * src[idx] + icp[idx];
                    if constexpr (MODE == 3) v = nonlin(v);
                }
                dst[idx] = v;
            }
        }
    }
}

extern "C" void kernel_launch(void* const* d_in, const int* in_sizes, int n_in,
                              void* d_out, int out_size, void* d_ws, size_t ws_size,
                              hipStream_t stream) {
    const float* x  = (const float*)d_in[0];
    const float* rw = (const float*)d_in[1];
    const float* rb = (const float*)d_in[2];
    const float* aw = (const float*)d_in[3];
    const float* ab = (const float*)d_in[4];
    const float* bw = (const float*)d_in[5];
    const float* bb = (const float*)d_in[6];
    const float* z  = (const float*)d_in[7];
    float* out = (float*)d_out;

    const size_t plane = (size_t)16 * NCH * HH * WW;   // 16.78M floats
    float* icp = (float*)d_ws;          // 0.1*(A_b + conv(x,B_w)+B_b+Z), f32
    float* s1  = icp + plane;           // state ping buffer (pong = d_out)

    // allow >64KB dynamic LDS (idempotent; ignore errors)
    (void)hipFuncSetAttribute(reinterpret_cast<const void*>(&cenn_conv<0>),
                              hipFuncAttributeMaxDynamicSharedMemorySize, LDS_BYTES);
    (void)hipFuncSetAttribute(reinterpret_cast<const void*>(&cenn_conv<1>),
                              hipFuncAttributeMaxDynamicSharedMemorySize, LDS_BYTES);
    (void)hipFuncSetAttribute(reinterpret_cast<const void*>(&cenn_conv<2>),
                              hipFuncAttributeMaxDynamicSharedMemorySize, LDS_BYTES);
    (void)hipFuncSetAttribute(reinterpret_cast<const void*>(&cenn_conv<3>),
                              hipFuncAttributeMaxDynamicSharedMemorySize, LDS_BYTES);

    dim3 blk(256, 1, 1), grd(WW / XS, HH / GROWS, 16);   // 2 x 16 x 16 = 512 blocks

    // state0 = conv(x, rescale_w) + rescale_b  -> d_out
    cenn_conv<0><<<grd, blk, LDS_BYTES, stream>>>(x, rw, rb, nullptr, nullptr, nullptr, out);
    // ICp = 0.1*(conv(x,B_w) + B_b + Z + A_b)  -> ws
    cenn_conv<1><<<grd, blk, LDS_BYTES, stream>>>(x, bw, bb, z, ab, nullptr, icp);

    for (int i = 0; i < 10; ++i) {
        const float* s = (i & 1) ? s1 : out;
        float*       d = (i & 1) ? out : s1;
        if (i == 9)
            cenn_conv<3><<<grd, blk, LDS_BYTES, stream>>>(s, aw, nullptr, nullptr, nullptr, icp, out);
        else
            cenn_conv<2><<<grd, blk, LDS_BYTES, stream>>>(s, aw, nullptr, nullptr, nullptr, icp, d);
    }
}

// Round 3
// 1160.284 us; speedup vs baseline: 12.4054x; 1.1111x over previous
//
#include <hip/hip_runtime.h>

// CeNN layer via bf16 MFMA implicit GEMM, v3.
// Passes: prep_w (frag-order weights), fused init (state0 + ICp), 10 iterations.
// Iter: dst = 0.9*src + 0.1*conv3x3(nonlin(src), A_w) + ICp
// ICp  = 0.1*(A_b + conv3x3(x,B_w) + B_b + Z)
// Block tile: 64 cout x 32 px wide x 8 rows; act in LDS (43.5 KB, XOR-swizzled),
// weights streamed from L2 (g_fw) into regs. 3 blocks/CU target.

typedef short  bf16x8 __attribute__((ext_vector_type(8)));
typedef float  f32x4  __attribute__((ext_vector_type(4)));

#define HH 128
#define WW 128
#define NCH 64
#define GROWS 8
#define NSLOT 10               // rows y0-1 .. y0+8
#define XS 32                  // output strip width
#define NC 34                  // staged cols x0-1 .. x0+32
#define ROWB 128               // 64 cin * 2B
#define SLOTB (NC * ROWB)      // 4352
#define ACTB (NSLOT * SLOTB)   // 43520
#define WSETB 73728            // one weight set, frag-ordered bf16

__device__ __align__(16) unsigned char g_fw[3 * WSETB];

__device__ __forceinline__ float nonlin(float x) {
    const float A = 0.01f;
    float y = fminf(x, fmaf(A, x, 1.0f - A));
    return fmaxf(y, fmaf(A, y, -(1.0f - A)));
}
__device__ __forceinline__ unsigned short f2bf(float f) {
    unsigned int u = __float_as_uint(f);
    u += 0x7fffu + ((u >> 16) & 1u);       // RNE
    return (unsigned short)(u >> 16);
}

// Transform w[cout][cin][3x3] -> fragment order.
// chunk = (cb*18+kb)*64+ln ; value j: k = kb*32+(ln>>4)*8+j ; k = tap*64+cin.
__global__ __launch_bounds__(256)
void prep_w(const float* __restrict__ rw, const float* __restrict__ bw,
            const float* __restrict__ aw) {
    const float* w = blockIdx.x == 0 ? rw : (blockIdx.x == 1 ? bw : aw);
    unsigned char* o = g_fw + blockIdx.x * WSETB;
    int chunk = blockIdx.y * 256 + threadIdx.x;        // 0..4607
    int cb  = chunk / 1152;
    int rem = chunk - cb * 1152;
    int kb  = rem >> 6;
    int ln  = rem & 63;
    int cout = cb * 16 + (ln & 15);
    int g    = ln >> 4;
    unsigned short h[8];
    #pragma unroll
    for (int j = 0; j < 8; ++j) {
        int k = kb * 32 + g * 8 + j;
        int tap = k >> 6;
        int cin = k & 63;
        h[j] = f2bf(w[(cout * 64 + cin) * 9 + tap]);
    }
    uint4 v;
    v.x = (unsigned)h[0] | ((unsigned)h[1] << 16);
    v.y = (unsigned)h[2] | ((unsigned)h[3] << 16);
    v.z = (unsigned)h[4] | ((unsigned)h[5] << 16);
    v.w = (unsigned)h[6] | ((unsigned)h[7] << 16);
    *(uint4*)(o + chunk * 16) = v;
}

__device__ __forceinline__ void conv_tile(const char* actl, const unsigned char* fw,
                                          int lane, int wv, f32x4 (&acc)[4][4]) {
    const int l15 = lane & 15;
    const int g4  = lane >> 4;
    #pragma unroll
    for (int kb = 0; kb < 18; ++kb) {
        const int tap  = kb >> 1;
        const int dy   = tap / 3;            // compile-time (unrolled)
        const int dx   = tap - dy * 3;
        const int cinB = (kb & 1) * 64 + g4 * 16;
        bf16x8 af[4];
        #pragma unroll
        for (int cb = 0; cb < 4; ++cb)
            af[cb] = *(const bf16x8*)(fw + ((cb * 18 + kb) * 64 + lane) * 16);
        bf16x8 bfr[4];
        #pragma unroll
        for (int i = 0; i < 4; ++i) {
            int row = wv * 2 + (i >> 1) + dy;
            int c   = (i & 1) * 16 + l15 + dx;
            bfr[i] = *(const bf16x8*)(actl + row * SLOTB + c * ROWB
                                      + (cinB ^ ((c & 7) << 4)));
        }
        #pragma unroll
        for (int cb = 0; cb < 4; ++cb)
            #pragma unroll
            for (int i = 0; i < 4; ++i)
                acc[cb][i] = __builtin_amdgcn_mfma_f32_16x16x32_bf16(
                    af[cb], bfr[i], acc[cb][i], 0, 0, 0);
    }
}

// MODE 0: fused init. dst=state0=conv(x,rw)+rb ; dst2=ICp=0.1*(conv(x,bw)+bb+z+ab)
// MODE 1: iteration.  dst = 0.1*conv(nonlin(src),aw) + 0.9*src + icp
// MODE 2: MODE 1 + final nonlin.
template<int MODE>
__global__ __launch_bounds__(256, 3)
void cenn(const float* __restrict__ src,
          const float* __restrict__ rb, const float* __restrict__ bb,
          const float* __restrict__ zz, const float* __restrict__ ab,
          const float* __restrict__ icp,
          float* __restrict__ dst, float* __restrict__ dst2)
{
    __shared__ __align__(16) char actl[ACTB];
    const int tid  = threadIdx.x;
    const int lane = tid & 63;
    const int wv   = tid >> 6;
    const int l15  = lane & 15;
    const int g4   = lane >> 4;
    const int x0   = blockIdx.x * XS;
    const int y0   = blockIdx.y * GROWS;
    const int n    = blockIdx.z;

    // ---- stage activations: [slot][col][cin] bf16, XOR-swizzled ----
    for (int idx = tid; idx < NSLOT * NC * 8; idx += 256) {
        int r   = idx / (NC * 8);
        int rem = idx - r * (NC * 8);
        int cb8 = rem / NC;
        int c   = rem - cb8 * NC;
        int y   = y0 + r - 1;
        int x   = x0 + c - 1;
        uint4 v = {0u, 0u, 0u, 0u};
        if ((unsigned)y < (unsigned)HH && (unsigned)x < (unsigned)WW) {
            const float* p = src + ((size_t)(n * NCH + cb8 * 8) * HH + y) * WW + x;
            unsigned short h[8];
            #pragma unroll
            for (int j = 0; j < 8; ++j) {
                float f = p[(size_t)j * HH * WW];
                if (MODE >= 1) f = nonlin(f);
                h[j] = f2bf(f);
            }
            v.x = (unsigned)h[0] | ((unsigned)h[1] << 16);
            v.y = (unsigned)h[2] | ((unsigned)h[3] << 16);
            v.z = (unsigned)h[4] | ((unsigned)h[5] << 16);
            v.w = (unsigned)h[6] | ((unsigned)h[7] << 16);
        }
        *(uint4*)(actl + r * SLOTB + c * ROWB + ((cb8 * 16) ^ ((c & 7) << 4))) = v;
    }
    __syncthreads();

    f32x4 acc[4][4];
    #pragma unroll
    for (int a = 0; a < 4; ++a)
        #pragma unroll
        for (int b = 0; b < 4; ++b)
            acc[a][b] = (f32x4){0.f, 0.f, 0.f, 0.f};

    conv_tile(actl, g_fw + (MODE == 0 ? 0 : 2 * WSETB), lane, wv, acc);

    if constexpr (MODE == 0) {
        // set 0: rescale conv -> state0
        #pragma unroll
        for (int cb = 0; cb < 4; ++cb)
            #pragma unroll
            for (int i = 0; i < 4; ++i) {
                int y = y0 + wv * 2 + (i >> 1);
                int x = x0 + (i & 1) * 16 + l15;
                #pragma unroll
                for (int r = 0; r < 4; ++r) {
                    int cout = cb * 16 + g4 * 4 + r;
                    size_t idx = ((size_t)(n * NCH + cout) * HH + y) * WW + x;
                    dst[idx] = acc[cb][i][r] + rb[cout];
                }
            }
        // set 1: B conv -> ICp
        #pragma unroll
        for (int a = 0; a < 4; ++a)
            #pragma unroll
            for (int b = 0; b < 4; ++b)
                acc[a][b] = (f32x4){0.f, 0.f, 0.f, 0.f};
        conv_tile(actl, g_fw + WSETB, lane, wv, acc);
        #pragma unroll
        for (int cb = 0; cb < 4; ++cb)
            #pragma unroll
            for (int i = 0; i < 4; ++i) {
                int y = y0 + wv * 2 + (i >> 1);
                int x = x0 + (i & 1) * 16 + l15;
                #pragma unroll
                for (int r = 0; r < 4; ++r) {
                    int cout = cb * 16 + g4 * 4 + r;
                    size_t idx = ((size_t)(n * NCH + cout) * HH + y) * WW + x;
                    dst2[idx] = 0.1f * (acc[cb][i][r] + bb[cout] + zz[cout] + ab[cout]);
                }
            }
    } else {
        #pragma unroll
        for (int cb = 0; cb < 4; ++cb)
            #pragma unroll
            for (int i = 0; i < 4; ++i) {
                int y = y0 + wv * 2 + (i >> 1);
                int x = x0 + (i & 1) * 16 + l15;
                #pragma unroll
                for (int r = 0; r < 4; ++r) {
                    int cout = cb * 16 + g4 * 4 + r;
                    size_t idx = ((size_t)(n * NCH + cout) * HH + y) * WW + x;
                    float v = 0.1f * acc[cb][i][r] + 0.9f * src[idx] + icp[idx];
                    if constexpr (MODE == 2) v = nonlin(v);
                    dst[idx] = v;
                }
            }
    }
}

extern "C" void kernel_launch(void* const* d_in, const int* in_sizes, int n_in,
                              void* d_out, int out_size, void* d_ws, size_t ws_size,
                              hipStream_t stream) {
    const float* x  = (const float*)d_in[0];
    const float* rw = (const float*)d_in[1];
    const float* rb = (const float*)d_in[2];
    const float* aw = (const float*)d_in[3];
    const float* ab = (const float*)d_in[4];
    const float* bw = (const float*)d_in[5];
    const float* bb = (const float*)d_in[6];
    const float* z  = (const float*)d_in[7];
    float* out = (float*)d_out;

    const size_t plane = (size_t)16 * NCH * HH * WW;   // 16.78M floats
    float* icp = (float*)d_ws;          // ICp plane (f32)
    float* s1  = icp + plane;           // state ping buffer (pong = d_out)

    dim3 blk(256, 1, 1), grd(WW / XS, HH / GROWS, 16);   // 4 x 16 x 16 = 1024 blocks

    prep_w<<<dim3(3, 18, 1), blk, 0, stream>>>(rw, bw, aw);
    // fused: state0 -> out, ICp -> icp
    cenn<0><<<grd, blk, 0, stream>>>(x, rb, bb, z, ab, nullptr, out, icp);

    for (int i = 0; i < 10; ++i) {
        const float* s = (i & 1) ? s1 : out;
        float*       d = (i & 1) ? out : s1;
        if (i == 9)
            cenn<2><<<grd, blk, 0, stream>>>(s, nullptr, nullptr, nullptr, nullptr, icp, out, nullptr);
        else
            cenn<1><<<grd, blk, 0, stream>>>(s, nullptr, nullptr, nullptr, nullptr, icp, d, nullptr);
    }
}

// Round 4
// 769.855 us; speedup vs baseline: 18.6967x; 1.5071x over previous
//
#include <hip/hip_runtime.h>

// CeNN layer, bf16 MFMA implicit GEMM, v4: NHWC intermediate state.
// prep_w; init (NCHW x -> state0 NHWC + ICp NHWC); 10 iters (NHWC->NHWC,
// last one writes NCHW d_out with final nonlin).
// Iter: dst = 0.9*src + 0.1*conv3x3(nonlin(src), A_w) + ICp

typedef short  bf16x8 __attribute__((ext_vector_type(8)));
typedef float  f32x4  __attribute__((ext_vector_type(4)));

#define HH 128
#define WW 128
#define NCH 64
#define GROWS 8
#define NSLOT 10               // rows y0-1 .. y0+8
#define XS 32                  // output strip width
#define NC 34                  // staged cols x0-1 .. x0+32
#define ROWB 128               // 64 cin * 2B
#define SLOTB (NC * ROWB)      // 4352
#define ACTB (NSLOT * SLOTB)   // 43520
#define WSETB 73728            // one frag-ordered bf16 weight set

__device__ __align__(16) unsigned char g_fw[3 * WSETB];

__device__ __forceinline__ float nonlin(float x) {
    const float A = 0.01f;
    float y = fminf(x, fmaf(A, x, 1.0f - A));
    return fmaxf(y, fmaf(A, y, -(1.0f - A)));
}
__device__ __forceinline__ unsigned int f2bf(float f) {
    unsigned int u = __float_as_uint(f);
    u += 0x7fffu + ((u >> 16) & 1u);       // RNE
    return u >> 16;
}

// w[cout][cin][3x3] -> fragment order. chunk=(cb*18+kb)*64+ln ;
// value j: k = kb*32+(ln>>4)*8+j ; k = tap*64+cin.
__global__ __launch_bounds__(256)
void prep_w(const float* __restrict__ rw, const float* __restrict__ bw,
            const float* __restrict__ aw) {
    const float* w = blockIdx.x == 0 ? rw : (blockIdx.x == 1 ? bw : aw);
    unsigned char* o = g_fw + blockIdx.x * WSETB;
    int chunk = blockIdx.y * 256 + threadIdx.x;        // 0..4607
    int cb  = chunk / 1152;
    int rem = chunk - cb * 1152;
    int kb  = rem >> 6;
    int ln  = rem & 63;
    int cout = cb * 16 + (ln & 15);
    int g    = ln >> 4;
    unsigned int h[8];
    #pragma unroll
    for (int j = 0; j < 8; ++j) {
        int k = kb * 32 + g * 8 + j;
        int tap = k >> 6;
        int cin = k & 63;
        h[j] = f2bf(w[(cout * 64 + cin) * 9 + tap]);
    }
    uint4 v;
    v.x = h[0] | (h[1] << 16);
    v.y = h[2] | (h[3] << 16);
    v.z = h[4] | (h[5] << 16);
    v.w = h[6] | (h[7] << 16);
    *(uint4*)(o + chunk * 16) = v;
}

__device__ __forceinline__ void conv_tile(const char* actl, const unsigned char* fw,
                                          int lane, int wv, f32x4 (&acc)[4][4]) {
    const int l15 = lane & 15;
    const int g4  = lane >> 4;
    #pragma unroll
    for (int kb = 0; kb < 18; ++kb) {
        const int tap  = kb >> 1;
        const int dy   = tap / 3;
        const int dx   = tap - dy * 3;
        const int cinB = (kb & 1) * 64 + g4 * 16;
        bf16x8 af[4];
        #pragma unroll
        for (int cb = 0; cb < 4; ++cb)
            af[cb] = *(const bf16x8*)(fw + ((cb * 18 + kb) * 64 + lane) * 16);
        bf16x8 bfr[4];
        #pragma unroll
        for (int i = 0; i < 4; ++i) {
            int row = wv * 2 + (i >> 1) + dy;
            int c   = (i & 1) * 16 + l15 + dx;
            bfr[i] = *(const bf16x8*)(actl + row * SLOTB + c * ROWB
                                      + (cinB ^ ((c & 7) << 4)));
        }
        #pragma unroll
        for (int cb = 0; cb < 4; ++cb)
            #pragma unroll
            for (int i = 0; i < 4; ++i)
                acc[cb][i] = __builtin_amdgcn_mfma_f32_16x16x32_bf16(
                    af[cb], bfr[i], acc[cb][i], 0, 0, 0);
    }
}

// MODE 0: init: src=x (NCHW). dst=state0 (NHWC)=conv(x,rw)+rb ;
//         dst2=ICp (NHWC)=0.1*(conv(x,bw)+bb+zz+ab)
// MODE 1: iter (NHWC->NHWC): dst = 0.1*conv(nonlin(src),aw)+0.9*src+icp
// MODE 2: final iter: MODE 1 + nonlin, dst written NCHW.
template<int MODE>
__global__ __launch_bounds__(256, 3)
void cenn(const float* __restrict__ src,
          const float* __restrict__ rb, const float* __restrict__ bb,
          const float* __restrict__ zz, const float* __restrict__ ab,
          const float* __restrict__ icp,
          float* __restrict__ dst, float* __restrict__ dst2)
{
    __shared__ __align__(16) char actl[ACTB];
    const int tid  = threadIdx.x;
    const int lane = tid & 63;
    const int wv   = tid >> 6;
    const int l15  = lane & 15;
    const int g4   = lane >> 4;

    // XCD-aware bijective swizzle: 1024 blocks, 128 per XCD chunk (2 images).
    int lin = (blockIdx.z * 16 + blockIdx.y) * 4 + blockIdx.x;
    lin = (lin & 7) * 128 + (lin >> 3);
    const int x0 = (lin & 3) * XS;
    const int y0 = ((lin >> 2) & 15) * GROWS;
    const int n  = lin >> 6;

    // ---- stage activations into [slot][col][cin] bf16, XOR-swizzled ----
    if constexpr (MODE == 0) {
        // x is NCHW: 8 plane-strided scalar loads per 16B chunk (one pass only)
        for (int idx = tid; idx < NSLOT * NC * 8; idx += 256) {
            int r   = idx / (NC * 8);
            int rem = idx - r * (NC * 8);
            int cb8 = rem / NC;
            int c   = rem - cb8 * NC;
            int y   = y0 + r - 1;
            int x   = x0 + c - 1;
            uint4 v = {0u, 0u, 0u, 0u};
            if ((unsigned)y < (unsigned)HH && (unsigned)x < (unsigned)WW) {
                const float* p = src + ((size_t)(n * NCH + cb8 * 8) * HH + y) * WW + x;
                unsigned int h[8];
                #pragma unroll
                for (int j = 0; j < 8; ++j)
                    h[j] = f2bf(p[(size_t)j * HH * WW]);
                v.x = h[0] | (h[1] << 16);
                v.y = h[2] | (h[3] << 16);
                v.z = h[4] | (h[5] << 16);
                v.w = h[6] | (h[7] << 16);
            }
            *(uint4*)(actl + r * SLOTB + c * ROWB + ((cb8 * 16) ^ ((c & 7) << 4))) = v;
        }
    } else {
        // src is NHWC: float4 = 4 consecutive cin at one pixel, fully coalesced
        for (int idx = tid; idx < NSLOT * NC * 16; idx += 256) {
            int r   = idx / (NC * 16);
            int rem = idx - r * (NC * 16);
            int c   = rem >> 4;
            int q   = rem & 15;
            int y   = y0 + r - 1;
            int x   = x0 + c - 1;
            uint2 w2 = {0u, 0u};
            if ((unsigned)y < (unsigned)HH && (unsigned)x < (unsigned)WW) {
                f32x4 v = *(const f32x4*)(src + ((((size_t)n * HH + y) * WW + x) << 6) + q * 4);
                w2.x = f2bf(nonlin(v[0])) | (f2bf(nonlin(v[1])) << 16);
                w2.y = f2bf(nonlin(v[2])) | (f2bf(nonlin(v[3])) << 16);
            }
            *(uint2*)(actl + r * SLOTB + c * ROWB + ((q * 8) ^ ((c & 7) << 4))) = w2;
        }
    }
    __syncthreads();

    f32x4 acc[4][4];
    #pragma unroll
    for (int a = 0; a < 4; ++a)
        #pragma unroll
        for (int b = 0; b < 4; ++b)
            acc[a][b] = (f32x4){0.f, 0.f, 0.f, 0.f};

    conv_tile(actl, g_fw + (MODE == 0 ? 0 : 2 * WSETB), lane, wv, acc);

    // D map per acc[cb][i]: pixel = l15 (fixed), couts cb*16+g4*4 + r (contiguous!)
    if constexpr (MODE == 0) {
        #pragma unroll
        for (int cb = 0; cb < 4; ++cb)
            #pragma unroll
            for (int i = 0; i < 4; ++i) {
                int y  = y0 + wv * 2 + (i >> 1);
                int x  = x0 + (i & 1) * 16 + l15;
                int c0 = cb * 16 + g4 * 4;
                size_t base = ((((size_t)n * HH + y) * WW + x) << 6) + c0;
                f32x4 o;
                #pragma unroll
                for (int r = 0; r < 4; ++r) o[r] = acc[cb][i][r] + rb[c0 + r];
                *(f32x4*)(dst + base) = o;
            }
        #pragma unroll
        for (int a = 0; a < 4; ++a)
            #pragma unroll
            for (int b = 0; b < 4; ++b)
                acc[a][b] = (f32x4){0.f, 0.f, 0.f, 0.f};
        conv_tile(actl, g_fw + WSETB, lane, wv, acc);
        #pragma unroll
        for (int cb = 0; cb < 4; ++cb)
            #pragma unroll
            for (int i = 0; i < 4; ++i) {
                int y  = y0 + wv * 2 + (i >> 1);
                int x  = x0 + (i & 1) * 16 + l15;
                int c0 = cb * 16 + g4 * 4;
                size_t base = ((((size_t)n * HH + y) * WW + x) << 6) + c0;
                f32x4 o;
                #pragma unroll
                for (int r = 0; r < 4; ++r)
                    o[r] = 0.1f * (acc[cb][i][r] + bb[c0 + r] + zz[c0 + r] + ab[c0 + r]);
                *(f32x4*)(dst2 + base) = o;
            }
    } else {
        #pragma unroll
        for (int cb = 0; cb < 4; ++cb)
            #pragma unroll
            for (int i = 0; i < 4; ++i) {
                int y  = y0 + wv * 2 + (i >> 1);
                int x  = x0 + (i & 1) * 16 + l15;
                int c0 = cb * 16 + g4 * 4;
                size_t base = ((((size_t)n * HH + y) * WW + x) << 6) + c0;
                f32x4 s = *(const f32x4*)(src + base);
                f32x4 p = *(const f32x4*)(icp + base);
                if constexpr (MODE == 1) {
                    f32x4 o;
                    #pragma unroll
                    for (int r = 0; r < 4; ++r)
                        o[r] = 0.1f * acc[cb][i][r] + 0.9f * s[r] + p[r];
                    *(f32x4*)(dst + base) = o;
                } else {
                    #pragma unroll
                    for (int r = 0; r < 4; ++r) {
                        float v = 0.1f * acc[cb][i][r] + 0.9f * s[r] + p[r];
                        v = nonlin(v);
                        dst[((size_t)(n * NCH + c0 + r) * HH + y) * WW + x] = v;
                    }
                }
            }
    }
}

extern "C" void kernel_launch(void* const* d_in, const int* in_sizes, int n_in,
                              void* d_out, int out_size, void* d_ws, size_t ws_size,
                              hipStream_t stream) {
    const float* x  = (const float*)d_in[0];
    const float* rw = (const float*)d_in[1];
    const float* rb = (const float*)d_in[2];
    const float* aw = (const float*)d_in[3];
    const float* ab = (const float*)d_in[4];
    const float* bw = (const float*)d_in[5];
    const float* bb = (const float*)d_in[6];
    const float* z  = (const float*)d_in[7];
    float* out = (float*)d_out;

    const size_t plane = (size_t)16 * NCH * HH * WW;   // 16.78M floats
    float* icp = (float*)d_ws;          // ICp plane, NHWC f32
    float* s1  = icp + plane;           // state ping buffer, NHWC f32

    dim3 blk(256, 1, 1), grd(4, 16, 16);   // 1024 blocks

    prep_w<<<dim3(3, 18, 1), blk, 0, stream>>>(rw, bw, aw);
    // state0 (NHWC) -> d_out(raw), ICp (NHWC) -> ws
    cenn<0><<<grd, blk, 0, stream>>>(x, rb, bb, z, ab, nullptr, out, icp);

    // parity: even i reads out, writes s1; odd i reads s1, writes out.
    // i=9 reads s1, writes NCHW final to out.
    for (int i = 0; i < 10; ++i) {
        const float* s = (i & 1) ? s1 : out;
        float*       d = (i & 1) ? out : s1;
        if (i == 9)
            cenn<2><<<grd, blk, 0, stream>>>(s, nullptr, nullptr, nullptr, nullptr, icp, out, nullptr);
        else
            cenn<1><<<grd, blk, 0, stream>>>(s, nullptr, nullptr, nullptr, nullptr, icp, d, nullptr);
    }
}